// Round 11
// baseline (14785.072 us; speedup 1.0000x reference)
//
#include <hip/hip_runtime.h>
#include <stdint.h>

typedef unsigned long long u64;
typedef unsigned u32;
typedef __attribute__((ext_vector_type(8))) _Float16 half8;  // 8 fp16 (4 VGPRs)
typedef __attribute__((ext_vector_type(4))) float f32x4;

// Problem constants
#define NROWS 16384   // B*H*W
#define CDIM  256
#define NEMB  8192

// d_out layout (float offsets): z | z_q | indices | one_hot
#define Z_OFF   0ull
#define ZQ_OFF  4194304ull
#define IDX_OFF 8388608ull
#define OH_OFF  8404992ull

// ws layout (total 8.25 MB, same footprint as the proven R6-R10 budget):
#define ES_OFF_BYTES     0        // es[8192] f32 (32 KB)
#define ZS_OFF_BYTES     32768    // zs[16384] f32 (64 KB)
#define ORIENT_OFF_BYTES 98304    // int
#define EH_OFF_BYTES     131072   // fp16 E, pre-tiled (4 MB)  [was keysA]
#define KEYSB_OFF_BYTES  4325376  // u32[16384*64] (4 MB)
// Scratch hosted in the one-hot tail (harness memsets out to 0 pre-launch):
//   del8 u64[16384][64] (8 MB) = one-hot rows 16128..16383 — read by k_final
//   blocks -> cleaned AFTER k_final by k_ohtail (also writes those rows' idx).
// ZH fp16 Z (8 MB) in the z_q output region (rewritten by k_final).
#define EHL_ROW0 16128

// E-scale: 512 = 2^9 exact; dot = acc/512, 2*dot = acc * 2^-8 exact.
#define ESCALE 512.0f
#define INV2SCALE 0.00390625f   // 2/512 = 2^-8, exact

#define THR_ULP 4u    // flag margin (|d~-d| <= ~1.5 grid ulps; 2E <= 4)
#define TRIP_ULP 8u   // per-row self-heal trip

// order-preserving f32 -> u32 map (monotone increasing)
__device__ __forceinline__ u32 fmap(float x) {
    u32 u = __float_as_uint(x);
    return (u & 0x80000000u) ? ~u : (u | 0x80000000u);
}
__device__ __forceinline__ u32 udiff(u32 a, u32 b) { return a > b ? a - b : b - a; }

// direct global->LDS DMA, 16B per lane (proven neutral-correct R1/R6-R10)
__device__ __forceinline__ void gload_lds16(const char* g, char* l) {
    __builtin_amdgcn_global_load_lds(
        (const __attribute__((address_space(1))) void*)(g),
        (__attribute__((address_space(3))) void*)(l), 16, 0, 0);
}

// ---------------------------------------------------------------------------
// Kernel A: transpose z_e [B,C,H,W] -> z [B,H,W,C]  (proven, verbatim)
// ---------------------------------------------------------------------------
__global__ __launch_bounds__(256) void k_transpose(const float* __restrict__ ze,
                                                   float* __restrict__ z) {
    __shared__ float T[64][65];
    int b = blockIdx.z, ct = blockIdx.x, ht = blockIdx.y;
    int c0 = ct * 64, hw0 = ht * 64;
    int lane = threadIdx.x & 63, grp = threadIdx.x >> 6;
    #pragma unroll
    for (int i = 0; i < 16; ++i) {
        int cl = grp + i * 4;
        T[cl][lane] = ze[((size_t)(b * 256 + c0 + cl)) * 1024 + hw0 + lane];
    }
    __syncthreads();
    #pragma unroll
    for (int i = 0; i < 16; ++i) {
        int hwl = grp + i * 4;
        z[((size_t)(b * 1024 + hw0 + hwl)) * 256 + c0 + lane] = T[lane][hwl];
    }
}

// ---------------------------------------------------------------------------
// numpy pairwise_sum emulation (proven bit-exact, verbatim)
// ---------------------------------------------------------------------------
__device__ __forceinline__ float pw128sq(const float* __restrict__ x) {
    float r[8];
    #pragma unroll
    for (int j = 0; j < 8; ++j) r[j] = __fmul_rn(x[j], x[j]);
    #pragma unroll
    for (int i = 8; i < 128; i += 8) {
        #pragma unroll
        for (int j = 0; j < 8; ++j)
            r[j] = __fadd_rn(r[j], __fmul_rn(x[i + j], x[i + j]));
    }
    return __fadd_rn(__fadd_rn(__fadd_rn(r[0], r[1]), __fadd_rn(r[2], r[3])),
                     __fadd_rn(__fadd_rn(r[4], r[5]), __fadd_rn(r[6], r[7])));
}

__global__ __launch_bounds__(256) void k_rowsq(const float* __restrict__ X,
                                               float* __restrict__ out,
                                               int nrows) {
    int r = blockIdx.x * 256 + threadIdx.x;
    if (r >= nrows) return;
    const float* x = &X[(size_t)r * 256];
    out[r] = __fadd_rn(pw128sq(x), pw128sq(x + 128));
}

__global__ __launch_bounds__(256) void k_zsq(const float* __restrict__ ze,
                                             float* __restrict__ zs) {
    int t = blockIdx.x * 256 + threadIdx.x;
    int b = t >> 10, hw = t & 1023;
    const float* base = ze + ((size_t)b * 256) * 1024 + hw;
    float half[2];
    #pragma unroll
    for (int hB = 0; hB < 2; ++hB) {
        const float* p = base + (size_t)(hB * 128) * 1024;
        float r[8];
        #pragma unroll
        for (int j = 0; j < 8; ++j) {
            float v = p[(size_t)j * 1024];
            r[j] = __fmul_rn(v, v);
        }
        #pragma unroll
        for (int i = 8; i < 128; i += 8) {
            #pragma unroll
            for (int j = 0; j < 8; ++j) {
                float v = p[(size_t)(i + j) * 1024];
                r[j] = __fadd_rn(r[j], __fmul_rn(v, v));
            }
        }
        half[hB] = __fadd_rn(__fadd_rn(__fadd_rn(r[0], r[1]), __fadd_rn(r[2], r[3])),
                             __fadd_rn(__fadd_rn(r[4], r[5]), __fadd_rn(r[6], r[7])));
    }
    zs[t] = __fadd_rn(half[0], half[1]);
}

// ---------------------------------------------------------------------------
// Kernel S16: X -> fp16(X*scale), pre-tiled [rowblock][kchunk(8)][p(4)][row128][16B]
// ---------------------------------------------------------------------------
__global__ __launch_bounds__(256) void k_split16(const float* __restrict__ X,
                                                 char* __restrict__ H,
                                                 int nrows, float scale) {
    int t = blockIdx.x * 256 + threadIdx.x;
    if (t >= nrows * 32) return;
    int row = t >> 5, c8 = t & 31;
    const float* src = X + (size_t)row * 256 + c8 * 8;
    float4 f0 = *(const float4*)src;
    float4 f1 = *(const float4*)(src + 4);
    float f[8] = {f0.x, f0.y, f0.z, f0.w, f1.x, f1.y, f1.z, f1.w};
    union { _Float16 h[8]; uint4 v; } u;
    #pragma unroll
    for (int j = 0; j < 8; ++j)
        u.h[j] = (_Float16)(f[j] * scale);
    int rb = row >> 7, rloc = row & 127, kc = c8 >> 2, p = c8 & 3;
    size_t base = ((size_t)(rb * 8 + kc)) * 8192 + (size_t)p * 2048 + (size_t)rloc * 16;
    *(uint4*)(H + base) = u.v;
}

// ---------------------------------------------------------------------------
// Kernel C: fp16 MFMA GEMM (R10-proven loop).  R11: hypB-only single-pass
// epilogue.  Lane holds (row rowhalf+rt*16+l15, cols colhalf+ct*16+p*4..+3);
// 4-col minima -> redS[row][colhalf*16+ct*4+p]; tid<128 folds slot pairs to
// 16x 8-col subgroup minima, chunk min (== old keysB value, bit-identical,
// orient vote unchanged) + 16x 4-bit sat deltas packed in del8 u64.
// ---------------------------------------------------------------------------
__global__ __launch_bounds__(256) void k_dist(const char* __restrict__ ZH,
                                              const char* __restrict__ EH,
                                              const float* __restrict__ es,
                                              const float* __restrict__ zs,
                                              u32* __restrict__ keysB,
                                              u64* __restrict__ del8) {
    __shared__ __align__(16) char smem[16896];   // staging 16KB ∪ redS [128][33]
    int L = blockIdx.x;                 // 0..8191 (XCD-chunked mapping, R10)
    int xcd = L & 7, idx = L >> 3;
    int bx = xcd * 8 + (idx & 7);       // col block 0..63
    int by = idx >> 3;                  // row block 0..127
    int tid = threadIdx.x;
    int w = tid >> 6, lane = tid & 63;
    int p = lane >> 4, l15 = lane & 15;
    int rowhalf = (w & 1) * 64, colhalf = (w >> 1) * 64;
    int row0 = by * 128, col0 = bx * 128;

    f32x4 acc[4][4] = {};

    const char* asrc = ZH + ((size_t)(by * 8)) * 8192;
    const char* bsrc = EH + ((size_t)(bx * 8)) * 8192;

    for (int kc = 0; kc < 8; ++kc) {
        if (kc) __syncthreads();
        const char* ak = asrc + (size_t)kc * 8192;
        const char* bk = bsrc + (size_t)kc * 8192;
        #pragma unroll
        for (int it = 0; it < 2; ++it) {
            int off = it * 4096 + tid * 16;
            gload_lds16(ak + off, smem + off);
        }
        #pragma unroll
        for (int it = 0; it < 2; ++it) {
            int off = it * 4096 + tid * 16;
            gload_lds16(bk + off, smem + 8192 + off);
        }
        __syncthreads();   // drains vmcnt: DMA writes visible

        half8 A[4], B[4];
        #pragma unroll
        for (int rt = 0; rt < 4; ++rt) {
            int r = rowhalf + rt * 16 + l15;
            A[rt] = *(const half8*)(smem + p * 2048 + r * 16);
        }
        #pragma unroll
        for (int ct = 0; ct < 4; ++ct) {
            int c = colhalf + ct * 16 + l15;
            B[ct] = *(const half8*)(smem + 8192 + p * 2048 + c * 16);
        }
        #pragma unroll
        for (int rt = 0; rt < 4; ++rt)
            #pragma unroll
            for (int ct = 0; ct < 4; ++ct)
                acc[rt][ct] = __builtin_amdgcn_mfma_f32_16x16x32_f16(
                    A[rt], B[ct], acc[rt][ct], 0, 0, 0);
    }
    __syncthreads();   // before smem reuse as redS

    u32* redS = (u32*)smem;   // [128][33]: slot = colhalf*16 + ct*4 + p

    float zsB4[4], esB[4][4];
    #pragma unroll
    for (int rt = 0; rt < 4; ++rt)
        zsB4[rt] = zs[row0 + rowhalf + rt * 16 + l15];
    #pragma unroll
    for (int ct = 0; ct < 4; ++ct)
        #pragma unroll
        for (int reg = 0; reg < 4; ++reg)
            esB[ct][reg] = es[col0 + colhalf + ct * 16 + p * 4 + reg];

    #pragma unroll
    for (int rt = 0; rt < 4; ++rt) {
        int rowloc = rowhalf + rt * 16 + l15;
        #pragma unroll
        for (int ct = 0; ct < 4; ++ct) {
            u32 m4 = 0xffffffffu;
            #pragma unroll
            for (int reg = 0; reg < 4; ++reg) {
                float a2 = __fmul_rn(acc[rt][ct][reg], INV2SCALE);
                float v = __fsub_rn(__fadd_rn(zsB4[rt], esB[ct][reg]), a2);
                u32 f = fmap(v);
                if (f < m4) m4 = f;
            }
            redS[rowloc * 33 + (w >> 1) * 16 + ct * 4 + p] = m4;
        }
    }
    __syncthreads();
    if (tid < 128) {
        u32 sg[16], m = 0xffffffffu;
        #pragma unroll
        for (int s = 0; s < 16; ++s) {
            u32 a = redS[tid * 33 + 2 * s];
            u32 b = redS[tid * 33 + 2 * s + 1];
            u32 v = a < b ? a : b;
            sg[s] = v;
            if (v < m) m = v;
        }
        u64 dword = 0;
        #pragma unroll
        for (int s = 0; s < 16; ++s) {
            u32 d = sg[s] - m;
            if (d > 15u) d = 15u;
            dword |= (u64)d << (4 * s);
        }
        keysB[((size_t)(row0 + tid)) * 64 + bx] = m;
        del8[((size_t)(row0 + tid)) * 64 + bx] = dword;
    }
}

// ---------------------------------------------------------------------------
// exact np-f32 distance key (proven chain; float4 loads, same FMA order)
// ---------------------------------------------------------------------------
__device__ __forceinline__ u64 exact_key4(const float* zrow, const float* __restrict__ E,
                                          const float* __restrict__ es, float zsn, int k) {
    const float4* e4 = (const float4*)&E[(size_t)k * 256];
    float dot = 0.0f;
    #pragma unroll 4
    for (int c4 = 0; c4 < 64; ++c4) {
        float4 ev = e4[c4];
        dot = fmaf(zrow[c4 * 4 + 0], ev.x, dot);
        dot = fmaf(zrow[c4 * 4 + 1], ev.y, dot);
        dot = fmaf(zrow[c4 * 4 + 2], ev.z, dot);
        dot = fmaf(zrow[c4 * 4 + 3], ev.w, dot);
    }
    float t1 = __fadd_rn(zsn, es[k]);
    float d  = __fsub_rn(t1, __fmul_rn(2.0f, dot));
    return ((u64)fmap(d) << 32) | (u32)k;
}

// ---------------------------------------------------------------------------
// Kernel O: verify hypB keys (row 0, 16 chunks, exact vote).  keysB values
// are bit-identical to R6-R10's -> same vote -> ori=1 expected.
// ori != 1 -> k_final full exact scan (slow-correct safety net).
// ---------------------------------------------------------------------------
__global__ __launch_bounds__(256) void k_orient(const float* __restrict__ Z,
                                                const float* __restrict__ E,
                                                const float* __restrict__ es,
                                                const float* __restrict__ zs,
                                                const u32* __restrict__ keysB,
                                                int* __restrict__ orient) {
    __shared__ float zrow[256];
    __shared__ u32 mex[256];
    int tid = threadIdx.x;
    zrow[tid] = Z[tid];   // row 0
    __syncthreads();
    int chunk = tid >> 4, sub = tid & 15;
    float zsn = zs[0];
    u32 best = 0xffffffffu;
    #pragma unroll 2
    for (int j = 0; j < 8; ++j) {
        u64 key = exact_key4(zrow, E, es, zsn, chunk * 128 + sub * 8 + j);
        u32 f = (u32)(key >> 32);
        if (f < best) best = f;
    }
    mex[tid] = best;
    __syncthreads();
    if (tid == 0) {
        int cB = 0;
        for (int s = 0; s < 16; ++s) {
            u32 m = 0xffffffffu;
            for (int t = 0; t < 16; ++t) { u32 v = mex[s * 16 + t]; if (v < m) m = v; }
            if (udiff(keysB[s], m) <= 2u) ++cB;
        }
        *orient = (cB >= 12) ? 1 : 2;
    }
}

// ---------------------------------------------------------------------------
// Kernel D: per-row finalize at 8-col-subgroup granularity.  Same proven
// trust model (every col with approx <= m+THR exact-evaluated: subgroup min
// <= approx => delta <= 4 < 15; sat-15 excludable since base >= m).
// Overflow (>256 subgroups) or ori!=1 -> full exact scan.  TRIP self-heal.
// ---------------------------------------------------------------------------
__global__ __launch_bounds__(256) void k_final(const float* __restrict__ Z,
                                               const float* __restrict__ E,
                                               const float* __restrict__ es,
                                               const float* __restrict__ zs,
                                               const u32* __restrict__ keysB,
                                               const u64* __restrict__ del8,
                                               const int* __restrict__ orient,
                                               float* __restrict__ zq,
                                               float* __restrict__ idxf,
                                               float* __restrict__ oh) {
    __shared__ float zrow[256];
    __shared__ u32 kch[64];
    __shared__ u64 dv[64];
    __shared__ u64 rmin[256];
    __shared__ short glist[256];
    __shared__ int ng;
    __shared__ int dofull;
    __shared__ u32 mval;
    __shared__ int strip;

    int n = blockIdx.x, tid = threadIdx.x;
    int ori = *orient;

    zrow[tid] = Z[(size_t)n * 256 + tid];
    if (tid < 64) {
        kch[tid] = keysB[(size_t)n * 64 + tid];
        dv[tid]  = del8[(size_t)n * 64 + tid];
    }
    __syncthreads();
    if (tid == 0) {
        dofull = (ori != 1);
        ng = 0; mval = 0;
        if (!dofull) {
            u32 m = 0xffffffffu;
            for (int s = 0; s < 64; ++s) if (kch[s] < m) m = kch[s];
            mval = m;
            u32 thr = m + THR_ULP;
            int cnt = 0, ovf = 0;
            for (int s = 0; s < 64 && !ovf; ++s) {
                u32 base = kch[s];
                if (base > thr) continue;
                u64 dw = dv[s];
                for (int g = 0; g < 16; ++g) {
                    u32 d = (u32)(dw >> (4 * g)) & 0xfu;
                    if (base + d <= thr) {
                        if (cnt == 256) { ovf = 1; break; }
                        glist[cnt++] = (short)(s * 16 + g);
                    }
                }
            }
            if (ovf) dofull = 1; else ng = cnt;
        }
    }
    __syncthreads();

    float zsn = zs[n];
    u64 best = ~0ull;
    if (dofull) {
        for (int i = tid; i < NEMB; i += 256) {
            u64 key = exact_key4(zrow, E, es, zsn, i);
            if (key < best) best = key;
        }
    } else {
        int tot = ng * 8;
        for (int i = tid; i < tot; i += 256) {
            int v = glist[i >> 3];
            u64 key = exact_key4(zrow, E, es, zsn,
                                 (v >> 4) * 128 + (v & 15) * 8 + (i & 7));
            if (key < best) best = key;
        }
    }
    rmin[tid] = best;
    __syncthreads();
    for (int s = 128; s > 0; s >>= 1) {
        if (tid < s) { if (rmin[tid + s] < rmin[tid]) rmin[tid] = rmin[tid + s]; }
        __syncthreads();
    }
    u64 ph1 = rmin[0];
    if (tid == 0)
        strip = (!dofull) && (udiff((u32)(ph1 >> 32), mval) > TRIP_ULP);
    __syncthreads();

    if (strip) {
        best = ~0ull;
        for (int i = tid; i < NEMB; i += 256) {
            u64 key = exact_key4(zrow, E, es, zsn, i);
            if (key < best) best = key;
        }
        rmin[tid] = best;
        __syncthreads();
        for (int s = 128; s > 0; s >>= 1) {
            if (tid < s) { if (rmin[tid + s] < rmin[tid]) rmin[tid] = rmin[tid + s]; }
            __syncthreads();
        }
    }
    int idx = (int)(rmin[0] & 0xffffffffu);

    if (tid < 64)
        *(float4*)&zq[(size_t)n * 256 + tid * 4] =
            *(const float4*)&E[(size_t)idx * 256 + tid * 4];
    if (tid == 0) {
        idxf[n] = (float)idx;
        // rows >= EHL_ROW0 host del8 (read by all blocks) -> k_ohtail cleans
        // and writes their one-hot AFTER this kernel.
        if (n < EHL_ROW0) oh[(size_t)n * NEMB + idx] = 1.0f;
    }
}

// ---------------------------------------------------------------------------
// Kernel T: clean the del8-hosting one-hot rows (16128..16383) after k_final:
// zero the row, then set its one-hot from idxf.  Stream-ordered after
// k_final, so no read/write race on del8.
// ---------------------------------------------------------------------------
__global__ __launch_bounds__(256) void k_ohtail(const float* __restrict__ idxf,
                                                float* __restrict__ oh) {
    int n = EHL_ROW0 + blockIdx.x;
    int tid = threadIdx.x;
    float* ohrow = oh + (size_t)n * NEMB;
    float4 z4 = make_float4(0.f, 0.f, 0.f, 0.f);
    #pragma unroll
    for (int it = 0; it < 8; ++it)
        *(float4*)&ohrow[(it * 256 + tid) * 4] = z4;
    __syncthreads();
    if (tid == 0)
        ohrow[(int)idxf[n]] = 1.0f;
}

// ---------------------------------------------------------------------------
extern "C" void kernel_launch(void* const* d_in, const int* in_sizes, int n_in,
                              void* d_out, int out_size, void* d_ws, size_t ws_size,
                              hipStream_t stream) {
    const float* ze  = (const float*)d_in[0];   // [16,256,32,32]
    const float* emb = (const float*)d_in[1];   // [8192,256]
    float* out = (float*)d_out;
    float* z    = out + Z_OFF;
    float* zq   = out + ZQ_OFF;
    float* idxf = out + IDX_OFF;
    float* oh   = out + OH_OFF;
    float* es    = (float*)((char*)d_ws + ES_OFF_BYTES);
    float* zs    = (float*)((char*)d_ws + ZS_OFF_BYTES);
    int*   orient= (int*)((char*)d_ws + ORIENT_OFF_BYTES);
    char*  EH    = (char*)d_ws + EH_OFF_BYTES;                 // 4 MB (ws)
    u32*   keysB = (u32*)((char*)d_ws + KEYSB_OFF_BYTES);      // 4 MB (ws)
    char*  ZH   = (char*)zq;                                   // 8 MB (z_q region)
    u64*   del8 = (u64*)(oh + (size_t)EHL_ROW0 * NEMB);        // 8 MB (one-hot tail)

    k_transpose<<<dim3(4, 16, 16), 256, 0, stream>>>(ze, z);
    k_zsq<<<NROWS / 256, 256, 0, stream>>>(ze, zs);
    k_rowsq<<<NEMB / 256, 256, 0, stream>>>(emb, es, NEMB);
    k_split16<<<NROWS * 32 / 256, 256, 0, stream>>>(z, ZH, NROWS, 1.0f);
    k_split16<<<NEMB * 32 / 256, 256, 0, stream>>>(emb, EH, NEMB, ESCALE);
    k_dist<<<8192, 256, 0, stream>>>(ZH, EH, es, zs, keysB, del8);
    k_orient<<<1, 256, 0, stream>>>(z, emb, es, zs, keysB, orient);
    k_final<<<NROWS, 256, 0, stream>>>(z, emb, es, zs, keysB, del8, orient,
                                       zq, idxf, oh);
    k_ohtail<<<NROWS - EHL_ROW0, 256, 0, stream>>>(idxf, oh);
}